// Round 6
// baseline (484.104 us; speedup 1.0000x reference)
//
#include <hip/hip_runtime.h>
#include <hip/hip_bf16.h>

typedef __attribute__((ext_vector_type(8))) short short8;
typedef __attribute__((ext_vector_type(8))) _Float16 half8;
typedef __attribute__((ext_vector_type(4))) float f32x4;

#define NROWS 32768
#define CDIM 1024
#define BNC 256
#define TOPK 128
#define NKT 32   // k_main K-tiles of 32

struct alignas(8) U4 { unsigned short x, y, z, w; };

__device__ __forceinline__ unsigned short f2bf(float f){
  union { float f; unsigned u; } v; v.f = f;
  unsigned r = v.u + 0x7FFFu + ((v.u >> 16) & 1u);
  return (unsigned short)(r >> 16);
}
__device__ __forceinline__ float bf2f(unsigned short h){
  union { unsigned u; float f; } v; v.u = ((unsigned)h) << 16;
  return v.f;
}
__device__ __forceinline__ unsigned short f2h(float f){
  _Float16 h = (_Float16)f;
  union { _Float16 h; unsigned short u; } v; v.h = h; return v.u;
}
__device__ __forceinline__ void gl16(const void* g, void* l){
  __builtin_amdgcn_global_load_lds((const __attribute__((address_space(1))) void*)g,
                                   (__attribute__((address_space(3))) void*)l, 16, 0, 0);
}
__device__ __forceinline__ unsigned ldsaddr(const void* p){
  return (unsigned)(uintptr_t)(const __attribute__((address_space(3))) void*)p;
}
// asm ds_read_b128: invisible to the waitcnt pass -> no auto vmcnt drains against
// outstanding global_load_lds. Correctness: explicit lgkmcnt(0) + sched_barrier(0)
// before the consuming MFMAs (rule #18).
__device__ __forceinline__ short8 dsr128(unsigned addr){
  short8 r;
  asm volatile("ds_read_b128 %0, %1" : "=v"(r) : "v"(addr));
  return r;
}
__device__ __forceinline__ half8 s2h(short8 s){ union { short8 s; half8 h; } u; u.s = s; return u.h; }

// XOR swizzle within rows of 64B (4 granules of 16B): granule g -> g ^ swzf(r).
// Involution: pre-swizzle global source at stage, swizzle offset at read. 2-way = free.
__device__ __forceinline__ int swzf(int r){ return (r & 3) ^ ((r >> 2) & 1); }
__device__ __forceinline__ int swz(int o){ return o ^ (swzf(o >> 6) << 4); }

// stage one [128 rows][32 k] tile (8 KB) into LDS (256-thread blocks)
__device__ __forceinline__ void stage_tile(const unsigned short* g0, int gstride,
                                           char* lds, int tid){
  #pragma unroll
  for (int i = 0; i < 2; ++i){
    int o = tid * 16 + i * 4096;
    int lb = swz(o);
    gl16((const char*)g0 + (lb >> 6) * gstride + (lb & 63), lds + o);
  }
}
__device__ __forceinline__ int frag_off(int ridx, int lane){
  return ridx * 64 + (((lane >> 4) ^ swzf(ridx)) << 4);
}

// ---------------- param prep ----------------
__global__ void k_wt(const float* __restrict__ W, unsigned short* __restrict__ Wt){
  __shared__ float t[32][33];
  int tx = threadIdx.x, ty = threadIdx.y;
  int bx = blockIdx.x * 32, by = blockIdx.y * 32;
  for (int i = ty; i < 32; i += 8)
    t[i][tx] = W[(by + i) * CDIM + bx + tx];
  __syncthreads();
  for (int i = ty; i < 32; i += 8)
    Wt[(bx + i) * CDIM + by + tx] = f2bf(t[tx][i]);
}

__global__ void k_ecast(const float* __restrict__ eo, const float* __restrict__ ei,
                        unsigned short* __restrict__ ho, unsigned short* __restrict__ hi){
  int i = blockIdx.x * 256 + threadIdx.x;
  ho[i] = f2h(eo[i]);
  hi[i] = f2h(ei[i]);
}

// ---------------- bottleneck: grouped conv + BN + GELU (fp16 out), plus x->bf16 ----------------
__global__ __launch_bounds__(256) void k_bottleneck(
    const float* __restrict__ x,
    const float* __restrict__ cwo, const float* __restrict__ cbo,
    const float* __restrict__ go,  const float* __restrict__ bto,
    const float* __restrict__ mo,  const float* __restrict__ vo,
    const float* __restrict__ cwi, const float* __restrict__ cbi,
    const float* __restrict__ gi,  const float* __restrict__ bti,
    const float* __restrict__ mi,  const float* __restrict__ vi,
    unsigned short* __restrict__ xbf,
    unsigned short* __restrict__ uo, unsigned short* __restrict__ ui)
{
  const int t = threadIdx.x;
  const int r0 = blockIdx.x * 8;
  float4 cwov = ((const float4*)cwo)[t];
  float4 cwiv = ((const float4*)cwi)[t];
  float sco = go[t] * rsqrtf(vo[t] + 1e-5f);
  float sho = bto[t] - mo[t] * sco;
  float cbov = cbo[t];
  float sci = gi[t] * rsqrtf(vi[t] + 1e-5f);
  float shi = bti[t] - mi[t] * sci;
  float cbiv = cbi[t];
  for (int r = 0; r < 8; ++r){
    int row = r0 + r;
    float4 xv = ((const float4*)x)[row * 256 + t];
    U4 xb; xb.x = f2bf(xv.x); xb.y = f2bf(xv.y); xb.z = f2bf(xv.z); xb.w = f2bf(xv.w);
    ((U4*)xbf)[row * 256 + t] = xb;
    float h = xv.x*cwov.x + xv.y*cwov.y + xv.z*cwov.z + xv.w*cwov.w + cbov;
    h = h * sco + sho;
    float u = 0.5f * h * (1.0f + erff(h * 0.70710678118654752f));
    uo[row*BNC + t] = f2h(u);
    h = xv.x*cwiv.x + xv.y*cwiv.y + xv.z*cwiv.z + xv.w*cwiv.w + cbiv;
    h = h * sci + shi;
    u = 0.5f * h * (1.0f + erff(h * 0.70710678118654752f));
    ui[row*BNC + t] = f2h(u);
  }
}

// ---------------- expand GEMM (fp16): L = U@E^T + eb ----------------
__global__ __launch_bounds__(256, 3) void k_expand(
    const unsigned short* __restrict__ u16, const unsigned short* __restrict__ e16,
    const float* __restrict__ eb, float* __restrict__ Lout)
{
  __shared__ alignas(16) char lds[3 * 16384];
  const int tid = threadIdx.x;
  const int lane = tid & 63, w = tid >> 6;
  const int wr = (w >> 1) * 64, wc = (w & 1) * 64;
  int id = blockIdx.x;
  int xcd = id & 7, slot = id >> 3;
  const int row0 = (xcd * 32 + (slot >> 3)) * 128;
  const int col0 = (slot & 7) * 128;
  f32x4 acc[4][4] = {};
  auto stage = [&](int h, int buf){
    char* b = lds + buf * 16384;
    stage_tile(u16 + row0 * BNC + h * 32, 512, b, tid);
    stage_tile(e16 + col0 * BNC + h * 32, 512, b + 8192, tid);
  };
  stage(0, 0);
  stage(1, 1);
  asm volatile("s_waitcnt vmcnt(4)" ::: "memory");
  __builtin_amdgcn_s_barrier();
  const unsigned lbase = ldsaddr(lds);
  const int NK = BNC / 32;
  for (int h = 0; h < NK; ++h){
    unsigned sl = lbase + (h % 3) * 16384;
    short8 af[4], bfr[4];
    #pragma unroll
    for (int m = 0; m < 4; ++m) af[m]  = dsr128(sl + frag_off(wr + m * 16 + (lane & 15), lane));
    #pragma unroll
    for (int n = 0; n < 4; ++n) bfr[n] = dsr128(sl + 8192 + frag_off(wc + n * 16 + (lane & 15), lane));
    if (h + 2 < NK) stage(h + 2, (h + 2) % 3);
    __builtin_amdgcn_s_barrier();
    asm volatile("s_waitcnt lgkmcnt(0)" ::: "memory");
    __builtin_amdgcn_sched_barrier(0);
    __builtin_amdgcn_s_setprio(1);
    #pragma unroll
    for (int m = 0; m < 4; ++m)
      #pragma unroll
      for (int n = 0; n < 4; ++n)
        acc[m][n] = __builtin_amdgcn_mfma_f32_16x16x32_f16(s2h(af[m]), s2h(bfr[n]), acc[m][n], 0, 0, 0);
    __builtin_amdgcn_s_setprio(0);
    if (h + 2 < NK)      asm volatile("s_waitcnt vmcnt(4)" ::: "memory");
    else if (h + 1 < NK) asm volatile("s_waitcnt vmcnt(0)" ::: "memory");
    __builtin_amdgcn_s_barrier();
  }
  #pragma unroll
  for (int n = 0; n < 4; ++n){
    int col = col0 + wc + n * 16 + (lane & 15);
    float ebv = eb[col];
    #pragma unroll
    for (int m = 0; m < 4; ++m){
      int row = row0 + wr + m * 16 + ((lane >> 4) << 2);
      #pragma unroll
      for (int r = 0; r < 4; ++r)
        Lout[(row + r) * CDIM + col] = acc[m][n][r] + ebv;
    }
  }
}

// ---------------- softmax + top-128 threshold + sparse score ----------------
template<bool WRITE_XS>
__global__ __launch_bounds__(256) void k_select(
    const float* __restrict__ Lg, const unsigned short* __restrict__ xg,
    unsigned short* __restrict__ obf)
{
  const int lane = threadIdx.x & 63;
  const int row = blockIdx.x * 4 + (threadIdx.x >> 6);
  const float* Lr = Lg + row * CDIM;
  float v[16];
  #pragma unroll
  for (int c = 0; c < 4; ++c){
    float4 t4 = ((const float4*)Lr)[c * 64 + lane];
    v[c*4+0] = t4.x; v[c*4+1] = t4.y; v[c*4+2] = t4.z; v[c*4+3] = t4.w;
  }
  float M = v[0];
  #pragma unroll
  for (int j = 1; j < 16; ++j) M = fmaxf(M, v[j]);
  #pragma unroll
  for (int off = 32; off > 0; off >>= 1) M = fmaxf(M, __shfl_xor(M, off));
  float S = 0.f;
  #pragma unroll
  for (int j = 0; j < 16; ++j) S += expf(v[j] - M);
  #pragma unroll
  for (int off = 32; off > 0; off >>= 1) S += __shfl_xor(S, off);
  unsigned kx[16];
  #pragma unroll
  for (int j = 0; j < 16; ++j){
    union { float f; unsigned u; } q; q.f = v[j];
    kx[j] = q.u ^ ((q.u & 0x80000000u) ? 0xFFFFFFFFu : 0x80000000u);
  }
  unsigned pref = 0;
  for (int bit = 31; bit >= 0; --bit){
    unsigned cand = pref | (1u << bit);
    int c = 0;
    #pragma unroll
    for (int j = 0; j < 16; ++j) c += (kx[j] >= cand) ? 1 : 0;
    #pragma unroll
    for (int off = 32; off > 0; off >>= 1) c += __shfl_xor(c, off);
    if (c >= TOPK) pref = cand;
  }
  float invS = 1.0f / S;
  #pragma unroll
  for (int c = 0; c < 4; ++c){
    U4 o;
    float sc[4];
    #pragma unroll
    for (int j = 0; j < 4; ++j){
      int jj = c*4 + j;
      sc[j] = (kx[jj] >= pref) ? expf(v[jj] - M) * invS : 0.f;
    }
    if (WRITE_XS){
      U4 xv = ((const U4*)(xg + row * CDIM))[c * 64 + lane];
      o.x = f2bf(bf2f(xv.x) * sc[0]); o.y = f2bf(bf2f(xv.y) * sc[1]);
      o.z = f2bf(bf2f(xv.z) * sc[2]); o.w = f2bf(bf2f(xv.w) * sc[3]);
    } else {
      o.x = f2bf(sc[0]); o.y = f2bf(sc[1]); o.z = f2bf(sc[2]); o.w = f2bf(sc[3]);
    }
    ((U4*)(obf + row * CDIM))[c * 64 + lane] = o;
  }
}

// ---------------- main dual-A GEMM: 4-slot lead-3 counted pipeline ----------------
// Tile 128x256, BK=32, 8 waves = 4 pairs (wave w: acc1, wave w+4: acc2, same 64x128
// sub-tile). 4 LDS slots x 32KB rotate; phase T=2kt+mh stages half mh of kt+3.
// vmcnt(6) each phase start (2 loads/phase, 3 phases allowed outstanding) proves
// landed-through phase T-4; with one end-barrier/phase this publishes kt across
// waves before any wave reads it. Tail: kt30 -> vmcnt(4), kt31 -> vmcnt(0).
__global__ __launch_bounds__(512, 2) void k_main(
    const unsigned short* __restrict__ xbf, const unsigned short* __restrict__ xsbf,
    const unsigned short* __restrict__ wt,  const unsigned short* __restrict__ sobf,
    const float* __restrict__ bias, float* __restrict__ out)
{
  __shared__ alignas(16) char lds[131072];
  const int tid = threadIdx.x;
  const int lane = tid & 63, wid = tid >> 6;
  const int pr = wid & 3, a2s = wid >> 2;
  const int wr = (pr >> 1) * 64, wc = (pr & 1) * 128;
  int id = blockIdx.x;
  int xcd = id & 7, sl = id >> 3;
  const int row0 = (xcd * 32 + (sl >> 2)) * 128;
  const int col0 = (sl & 3) * 256;
  const char* a1p = (const char*)xbf;
  const char* a2p = (const char*)xsbf;
  const char* bp  = (const char*)wt;
  f32x4 acc[4][8] = {};

  auto stgA = [&](int kt, char* slot){
    int o = tid * 16;
    int lb = swz(o);
    size_t src = (size_t)(row0 + (lb >> 6)) * 2048 + (size_t)kt * 64 + (lb & 63);
    gl16(a1p + src, slot + o);
    gl16(a2p + src, slot + 8192 + o);
  };
  auto stgB = [&](int kt, char* slot){
    #pragma unroll
    for (int i = 0; i < 2; ++i){
      int o = i * 8192 + tid * 16;
      int lb = swz(o);
      gl16(bp + (size_t)(col0 + (lb >> 6)) * 2048 + (size_t)kt * 64 + (lb & 63),
           slot + 16384 + o);
    }
  };

  // prologue: kt0,kt1,kt2 into slots 0,1,2 (12 loads); own-kt0 landed + publish
  stgA(0, lds);         stgB(0, lds);
  stgA(1, lds + 32768); stgB(1, lds + 32768);
  stgA(2, lds + 65536); stgB(2, lds + 65536);
  asm volatile("s_waitcnt vmcnt(8)" ::: "memory");
  __builtin_amdgcn_s_barrier();
  const unsigned lbase = ldsaddr(lds);

  for (int kt = 0; kt < NKT; ++kt){
    const unsigned slr = lbase + (kt & 3) * 32768;
    char* slw = lds + ((kt + 3) & 3) * 32768;
    const unsigned abase = slr + a2s * 8192;
    const unsigned bbase = slr + 16384;
    short8 af0, af1, bfr[8];
    // ---- phase mh=0: acc rows 0-31 of wave tile, read B ----
    if (kt < 30)       asm volatile("s_waitcnt vmcnt(6)" ::: "memory");
    else if (kt == 30) asm volatile("s_waitcnt vmcnt(4)" ::: "memory");
    else               asm volatile("s_waitcnt vmcnt(0)" ::: "memory");
    af0 = dsr128(abase + frag_off(wr + 0*16 + (lane & 15), lane));
    af1 = dsr128(abase + frag_off(wr + 1*16 + (lane & 15), lane));
    #pragma unroll
    for (int n = 0; n < 8; ++n)
      bfr[n] = dsr128(bbase + frag_off(wc + n*16 + (lane & 15), lane));
    if (kt < 29) stgA(kt + 3, slw);
    asm volatile("s_waitcnt lgkmcnt(0)" ::: "memory");
    __builtin_amdgcn_sched_barrier(0);
    __builtin_amdgcn_s_setprio(1);
    #pragma unroll
    for (int n = 0; n < 8; ++n){
      acc[0][n] = __builtin_amdgcn_mfma_f32_16x16x32_bf16(af0, bfr[n], acc[0][n], 0, 0, 0);
      acc[1][n] = __builtin_amdgcn_mfma_f32_16x16x32_bf16(af1, bfr[n], acc[1][n], 0, 0, 0);
    }
    __builtin_amdgcn_s_setprio(0);
    __builtin_amdgcn_s_barrier();
    // ---- phase mh=1: acc rows 32-63, reuse B ----
    if (kt < 30)       asm volatile("s_waitcnt vmcnt(6)" ::: "memory");
    else if (kt == 30) asm volatile("s_waitcnt vmcnt(4)" ::: "memory");
    else               asm volatile("s_waitcnt vmcnt(0)" ::: "memory");
    af0 = dsr128(abase + frag_off(wr + 2*16 + (lane & 15), lane));
    af1 = dsr128(abase + frag_off(wr + 3*16 + (lane & 15), lane));
    if (kt < 29) stgB(kt + 3, slw);
    asm volatile("s_waitcnt lgkmcnt(0)" ::: "memory");
    __builtin_amdgcn_sched_barrier(0);
    __builtin_amdgcn_s_setprio(1);
    #pragma unroll
    for (int n = 0; n < 8; ++n){
      acc[2][n] = __builtin_amdgcn_mfma_f32_16x16x32_bf16(af0, bfr[n], acc[2][n], 0, 0, 0);
      acc[3][n] = __builtin_amdgcn_mfma_f32_16x16x32_bf16(af1, bfr[n], acc[3][n], 0, 0, 0);
    }
    __builtin_amdgcn_s_setprio(0);
    __builtin_amdgcn_s_barrier();
  }

  // ---- epilogue: waves 4-7 publish acc2 via LDS; waves 0-3 combine + store ----
  if (wid >= 4){
    char* base = lds + (wid - 4) * 32768;
    #pragma unroll
    for (int m = 0; m < 4; ++m)
      #pragma unroll
      for (int n = 0; n < 8; ++n)
        *(f32x4*)(base + (((m*8 + n) * 64 + lane) << 4)) = acc[m][n];
  }
  __syncthreads();
  if (wid < 4){
    const char* base = lds + wid * 32768;
    #pragma unroll
    for (int n = 0; n < 8; ++n){
      int col = col0 + wc + n*16 + (lane & 15);
      float bv = bias[col];
      #pragma unroll
      for (int m = 0; m < 4; ++m){
        int row = row0 + wr + m*16 + ((lane >> 4) << 2);
        f32x4 c2 = *(const f32x4*)(base + (((m*8 + n) * 64 + lane) << 4));
        #pragma unroll
        for (int j = 0; j < 4; ++j){
          float so = bf2f(sobf[(size_t)(row + j) * CDIM + col]);
          out[(size_t)(row + j) * CDIM + col] = acc[m][n][j] * so + c2[j] + bv;
        }
      }
    }
  }
}

extern "C" void kernel_launch(void* const* d_in, const int* in_sizes, int n_in,
                              void* d_out, int out_size, void* d_ws, size_t ws_size,
                              hipStream_t stream)
{
  const float* x    = (const float*)d_in[0];
  const float* W    = (const float*)d_in[1];
  const float* bias = (const float*)d_in[2];
  const float* cwo  = (const float*)d_in[3];
  const float* cbo  = (const float*)d_in[4];
  const float* bngo = (const float*)d_in[5];
  const float* bnbo = (const float*)d_in[6];
  const float* bnmo = (const float*)d_in[7];
  const float* bnvo = (const float*)d_in[8];
  const float* ewo  = (const float*)d_in[9];
  const float* ebo  = (const float*)d_in[10];
  const float* cwi  = (const float*)d_in[11];
  const float* cbi  = (const float*)d_in[12];
  const float* bngi = (const float*)d_in[13];
  const float* bnbi = (const float*)d_in[14];
  const float* bnmi = (const float*)d_in[15];
  const float* bnvi = (const float*)d_in[16];
  const float* ewi  = (const float*)d_in[17];
  const float* ebi  = (const float*)d_in[18];
  float* out = (float*)d_out;
  (void)in_sizes; (void)n_in; (void)out_size; (void)ws_size;

  char* ws = (char*)d_ws;
  size_t off = 0;
  auto alloc = [&](size_t bytes){ void* p = ws + off; off += (bytes + 255) & ~(size_t)255; return p; };
  unsigned short* xbf  = (unsigned short*)alloc((size_t)NROWS * CDIM * 2);
  unsigned short* xsbf = (unsigned short*)alloc((size_t)NROWS * CDIM * 2);
  unsigned short* sobf = (unsigned short*)alloc((size_t)NROWS * CDIM * 2);
  float*          Lbuf = (float*)         alloc((size_t)NROWS * CDIM * 4);
  unsigned short* uo   = (unsigned short*)alloc((size_t)NROWS * BNC * 2);
  unsigned short* ui   = (unsigned short*)alloc((size_t)NROWS * BNC * 2);
  unsigned short* wtb  = (unsigned short*)alloc((size_t)CDIM * CDIM * 2);
  unsigned short* e16o = (unsigned short*)alloc((size_t)CDIM * BNC * 2);
  unsigned short* e16i = (unsigned short*)alloc((size_t)CDIM * BNC * 2);

  k_wt<<<dim3(32, 32), dim3(32, 8), 0, stream>>>(W, wtb);
  k_ecast<<<dim3(1024), dim3(256), 0, stream>>>(ewo, ewi, e16o, e16i);
  k_bottleneck<<<dim3(NROWS / 8), dim3(256), 0, stream>>>(
      x, cwo, cbo, bngo, bnbo, bnmo, bnvo,
      cwi, cbi, bngi, bnbi, bnmi, bnvi, xbf, uo, ui);
  k_expand<<<dim3(2048), dim3(256), 0, stream>>>(uo, e16o, ebo, Lbuf);
  k_select<false><<<dim3(NROWS / 4), dim3(256), 0, stream>>>(Lbuf, nullptr, sobf);
  k_expand<<<dim3(2048), dim3(256), 0, stream>>>(ui, e16i, ebi, Lbuf);
  k_select<true><<<dim3(NROWS / 4), dim3(256), 0, stream>>>(Lbuf, xbf, xsbf);
  k_main<<<dim3(1024), dim3(512), 0, stream>>>(xbf, xsbf, wtb, sobf, bias, out);
}

// Round 8
// 478.090 us; speedup vs baseline: 1.0126x; 1.0126x over previous
//
#include <hip/hip_runtime.h>
#include <hip/hip_bf16.h>

typedef __attribute__((ext_vector_type(8))) short short8;
typedef __attribute__((ext_vector_type(8))) _Float16 half8;
typedef __attribute__((ext_vector_type(4))) float f32x4;

#define NROWS 32768
#define CDIM 1024
#define BNC 256
#define TOPK 128
#define NKT 32   // k_main K-tiles of 32

struct alignas(8) U4 { unsigned short x, y, z, w; };

__device__ __forceinline__ unsigned short f2bf(float f){
  union { float f; unsigned u; } v; v.f = f;
  unsigned r = v.u + 0x7FFFu + ((v.u >> 16) & 1u);
  return (unsigned short)(r >> 16);
}
__device__ __forceinline__ float bf2f(unsigned short h){
  union { unsigned u; float f; } v; v.u = ((unsigned)h) << 16;
  return v.f;
}
__device__ __forceinline__ unsigned short f2h(float f){
  _Float16 h = (_Float16)f;
  union { _Float16 h; unsigned short u; } v; v.h = h; return v.u;
}
__device__ __forceinline__ void gl16(const void* g, void* l){
  __builtin_amdgcn_global_load_lds((const __attribute__((address_space(1))) void*)g,
                                   (__attribute__((address_space(3))) void*)l, 16, 0, 0);
}
__device__ __forceinline__ unsigned ldsaddr(const void* p){
  return (unsigned)(uintptr_t)(const __attribute__((address_space(3))) void*)p;
}
// asm ds_read_b128: invisible to the waitcnt pass -> no auto vmcnt drains against
// outstanding global_load_lds. Correctness: explicit lgkmcnt(0) + sched_barrier(0)
// before the consuming MFMAs (rule #18).
__device__ __forceinline__ short8 dsr128(unsigned addr){
  short8 r;
  asm volatile("ds_read_b128 %0, %1" : "=v"(r) : "v"(addr));
  return r;
}
__device__ __forceinline__ half8 s2h(short8 s){ union { short8 s; half8 h; } u; u.s = s; return u.h; }

// XOR swizzle within rows of 64B (4 granules of 16B): granule g -> g ^ swzf(r).
// Involution: pre-swizzle global source at stage, swizzle offset at read. 2-way = free.
__device__ __forceinline__ int swzf(int r){ return (r & 3) ^ ((r >> 2) & 1); }
__device__ __forceinline__ int swz(int o){ return o ^ (swzf(o >> 6) << 4); }

// stage one [128 rows][32 k] tile (8 KB) into LDS (256-thread blocks)
__device__ __forceinline__ void stage_tile(const unsigned short* g0, int gstride,
                                           char* lds, int tid){
  #pragma unroll
  for (int i = 0; i < 2; ++i){
    int o = tid * 16 + i * 4096;
    int lb = swz(o);
    gl16((const char*)g0 + (lb >> 6) * gstride + (lb & 63), lds + o);
  }
}
__device__ __forceinline__ int frag_off(int ridx, int lane){
  return ridx * 64 + (((lane >> 4) ^ swzf(ridx)) << 4);
}

// ---------------- param prep ----------------
__global__ void k_wt(const float* __restrict__ W, unsigned short* __restrict__ Wt){
  __shared__ float t[32][33];
  int tx = threadIdx.x, ty = threadIdx.y;
  int bx = blockIdx.x * 32, by = blockIdx.y * 32;
  for (int i = ty; i < 32; i += 8)
    t[i][tx] = W[(by + i) * CDIM + bx + tx];
  __syncthreads();
  for (int i = ty; i < 32; i += 8)
    Wt[(bx + i) * CDIM + by + tx] = f2bf(t[tx][i]);
}

__global__ void k_ecast(const float* __restrict__ eo, const float* __restrict__ ei,
                        unsigned short* __restrict__ ho, unsigned short* __restrict__ hi){
  int i = blockIdx.x * 256 + threadIdx.x;
  ho[i] = f2h(eo[i]);
  hi[i] = f2h(ei[i]);
}

// ---------------- bottleneck: grouped conv + BN + GELU (fp16 out), plus x->bf16 ----------------
__global__ __launch_bounds__(256) void k_bottleneck(
    const float* __restrict__ x,
    const float* __restrict__ cwo, const float* __restrict__ cbo,
    const float* __restrict__ go,  const float* __restrict__ bto,
    const float* __restrict__ mo,  const float* __restrict__ vo,
    const float* __restrict__ cwi, const float* __restrict__ cbi,
    const float* __restrict__ gi,  const float* __restrict__ bti,
    const float* __restrict__ mi,  const float* __restrict__ vi,
    unsigned short* __restrict__ xbf,
    unsigned short* __restrict__ uo, unsigned short* __restrict__ ui)
{
  const int t = threadIdx.x;
  const int r0 = blockIdx.x * 8;
  float4 cwov = ((const float4*)cwo)[t];
  float4 cwiv = ((const float4*)cwi)[t];
  float sco = go[t] * rsqrtf(vo[t] + 1e-5f);
  float sho = bto[t] - mo[t] * sco;
  float cbov = cbo[t];
  float sci = gi[t] * rsqrtf(vi[t] + 1e-5f);
  float shi = bti[t] - mi[t] * sci;
  float cbiv = cbi[t];
  for (int r = 0; r < 8; ++r){
    int row = r0 + r;
    float4 xv = ((const float4*)x)[row * 256 + t];
    U4 xb; xb.x = f2bf(xv.x); xb.y = f2bf(xv.y); xb.z = f2bf(xv.z); xb.w = f2bf(xv.w);
    ((U4*)xbf)[row * 256 + t] = xb;
    float h = xv.x*cwov.x + xv.y*cwov.y + xv.z*cwov.z + xv.w*cwov.w + cbov;
    h = h * sco + sho;
    float u = 0.5f * h * (1.0f + erff(h * 0.70710678118654752f));
    uo[row*BNC + t] = f2h(u);
    h = xv.x*cwiv.x + xv.y*cwiv.y + xv.z*cwiv.z + xv.w*cwiv.w + cbiv;
    h = h * sci + shi;
    u = 0.5f * h * (1.0f + erff(h * 0.70710678118654752f));
    ui[row*BNC + t] = f2h(u);
  }
}

// ---------------- expand GEMM (fp16): L = U@E^T + eb ---------------- (round-6 known-good)
__global__ __launch_bounds__(256, 3) void k_expand(
    const unsigned short* __restrict__ u16, const unsigned short* __restrict__ e16,
    const float* __restrict__ eb, float* __restrict__ Lout)
{
  __shared__ alignas(16) char lds[3 * 16384];
  const int tid = threadIdx.x;
  const int lane = tid & 63, w = tid >> 6;
  const int wr = (w >> 1) * 64, wc = (w & 1) * 64;
  int id = blockIdx.x;
  int xcd = id & 7, slot = id >> 3;
  const int row0 = (xcd * 32 + (slot >> 3)) * 128;
  const int col0 = (slot & 7) * 128;
  f32x4 acc[4][4] = {};
  auto stage = [&](int h, int buf){
    char* b = lds + buf * 16384;
    stage_tile(u16 + row0 * BNC + h * 32, 512, b, tid);
    stage_tile(e16 + col0 * BNC + h * 32, 512, b + 8192, tid);
  };
  stage(0, 0);
  stage(1, 1);
  asm volatile("s_waitcnt vmcnt(4)" ::: "memory");
  __builtin_amdgcn_s_barrier();
  const unsigned lbase = ldsaddr(lds);
  const int NK = BNC / 32;
  for (int h = 0; h < NK; ++h){
    unsigned sl = lbase + (h % 3) * 16384;
    short8 af[4], bfr[4];
    #pragma unroll
    for (int m = 0; m < 4; ++m) af[m]  = dsr128(sl + frag_off(wr + m * 16 + (lane & 15), lane));
    #pragma unroll
    for (int n = 0; n < 4; ++n) bfr[n] = dsr128(sl + 8192 + frag_off(wc + n * 16 + (lane & 15), lane));
    if (h + 2 < NK) stage(h + 2, (h + 2) % 3);
    __builtin_amdgcn_s_barrier();
    asm volatile("s_waitcnt lgkmcnt(0)" ::: "memory");
    __builtin_amdgcn_sched_barrier(0);
    __builtin_amdgcn_s_setprio(1);
    #pragma unroll
    for (int m = 0; m < 4; ++m)
      #pragma unroll
      for (int n = 0; n < 4; ++n)
        acc[m][n] = __builtin_amdgcn_mfma_f32_16x16x32_f16(s2h(af[m]), s2h(bfr[n]), acc[m][n], 0, 0, 0);
    __builtin_amdgcn_s_setprio(0);
    if (h + 2 < NK)      asm volatile("s_waitcnt vmcnt(4)" ::: "memory");
    else if (h + 1 < NK) asm volatile("s_waitcnt vmcnt(0)" ::: "memory");
    __builtin_amdgcn_s_barrier();
  }
  #pragma unroll
  for (int n = 0; n < 4; ++n){
    int col = col0 + wc + n * 16 + (lane & 15);
    float ebv = eb[col];
    #pragma unroll
    for (int m = 0; m < 4; ++m){
      int row = row0 + wr + m * 16 + ((lane >> 4) << 2);
      #pragma unroll
      for (int r = 0; r < 4; ++r)
        Lout[(row + r) * CDIM + col] = acc[m][n][r] + ebv;
    }
  }
}

// ---------------- softmax + top-128 threshold + sparse score ----------------
template<bool WRITE_XS>
__global__ __launch_bounds__(256) void k_select(
    const float* __restrict__ Lg, const unsigned short* __restrict__ xg,
    unsigned short* __restrict__ obf)
{
  const int lane = threadIdx.x & 63;
  const int row = blockIdx.x * 4 + (threadIdx.x >> 6);
  const float* Lr = Lg + row * CDIM;
  float v[16];
  #pragma unroll
  for (int c = 0; c < 4; ++c){
    float4 t4 = ((const float4*)Lr)[c * 64 + lane];
    v[c*4+0] = t4.x; v[c*4+1] = t4.y; v[c*4+2] = t4.z; v[c*4+3] = t4.w;
  }
  float M = v[0];
  #pragma unroll
  for (int j = 1; j < 16; ++j) M = fmaxf(M, v[j]);
  #pragma unroll
  for (int off = 32; off > 0; off >>= 1) M = fmaxf(M, __shfl_xor(M, off));
  float S = 0.f;
  #pragma unroll
  for (int j = 0; j < 16; ++j) S += expf(v[j] - M);
  #pragma unroll
  for (int off = 32; off > 0; off >>= 1) S += __shfl_xor(S, off);
  unsigned kx[16];
  #pragma unroll
  for (int j = 0; j < 16; ++j){
    union { float f; unsigned u; } q; q.f = v[j];
    kx[j] = q.u ^ ((q.u & 0x80000000u) ? 0xFFFFFFFFu : 0x80000000u);
  }
  unsigned pref = 0;
  for (int bit = 31; bit >= 0; --bit){
    unsigned cand = pref | (1u << bit);
    int c = 0;
    #pragma unroll
    for (int j = 0; j < 16; ++j) c += (kx[j] >= cand) ? 1 : 0;
    #pragma unroll
    for (int off = 32; off > 0; off >>= 1) c += __shfl_xor(c, off);
    if (c >= TOPK) pref = cand;
  }
  float invS = 1.0f / S;
  #pragma unroll
  for (int c = 0; c < 4; ++c){
    U4 o;
    float sc[4];
    #pragma unroll
    for (int j = 0; j < 4; ++j){
      int jj = c*4 + j;
      sc[j] = (kx[jj] >= pref) ? expf(v[jj] - M) * invS : 0.f;
    }
    if (WRITE_XS){
      U4 xv = ((const U4*)(xg + row * CDIM))[c * 64 + lane];
      o.x = f2bf(bf2f(xv.x) * sc[0]); o.y = f2bf(bf2f(xv.y) * sc[1]);
      o.z = f2bf(bf2f(xv.z) * sc[2]); o.w = f2bf(bf2f(xv.w) * sc[3]);
    } else {
      o.x = f2bf(sc[0]); o.y = f2bf(sc[1]); o.z = f2bf(sc[2]); o.w = f2bf(sc[3]);
    }
    ((U4*)(obf + row * CDIM))[c * 64 + lane] = o;
  }
}

// ---------------- main dual-A GEMM: 128x128, 3-slot lead-2, 2 blocks/CU ----------------
// 256 thr / 4 waves. Slot = A1 8K + A2 8K + B 8K = 24 KB; 3 slots = 72 KB -> 2 blocks/CU
// co-resident (cross-block overlap hides ds_read latency + barrier slop). ONE barrier and
// ONE counted vmcnt per K-step: per kt each wave issues 6 staging loads (lead-2);
// end-of-kt vmcnt(6) drains kt-1's loads -> publishes slot kt+1 at the barrier.
// Tail: kt==NKT-2 -> vmcnt(0) publishes the last slot; kt==NKT-1 no wait.
__global__ __launch_bounds__(256, 2) void k_main(
    const unsigned short* __restrict__ xbf, const unsigned short* __restrict__ xsbf,
    const unsigned short* __restrict__ wt,  const unsigned short* __restrict__ sobf,
    const float* __restrict__ bias, float* __restrict__ out)
{
  __shared__ alignas(16) char lds[3 * 24576];
  const int tid = threadIdx.x;
  const int lane = tid & 63, w = tid >> 6;
  const int wr = (w >> 1) * 64, wc = (w & 1) * 64;
  int id = blockIdx.x;
  int xcd = id & 7, sl = id >> 3;
  const int row0 = (xcd * 32 + (sl >> 3)) * 128;
  const int col0 = (sl & 7) * 128;
  f32x4 acc1[4][4] = {}, acc2[4][4] = {};
  auto stage = [&](int kt, int buf){
    char* b = lds + buf * 24576;
    stage_tile(xbf  + row0 * CDIM + kt * 32, 2048, b, tid);
    stage_tile(xsbf + row0 * CDIM + kt * 32, 2048, b + 8192, tid);
    stage_tile(wt   + col0 * CDIM + kt * 32, 2048, b + 16384, tid);
  };
  stage(0, 0);
  stage(1, 1);
  asm volatile("s_waitcnt vmcnt(6)" ::: "memory");
  __builtin_amdgcn_s_barrier();
  const unsigned lbase = ldsaddr(lds);
  for (int kt = 0; kt < NKT; ++kt){
    const unsigned slr = lbase + (kt % 3) * 24576;
    short8 a1f[4], a2f[4], bfr[4];
    #pragma unroll
    for (int m = 0; m < 4; ++m){
      int fo = frag_off(wr + m * 16 + (lane & 15), lane);
      a1f[m] = dsr128(slr + fo);
      a2f[m] = dsr128(slr + 8192 + fo);
    }
    #pragma unroll
    for (int n = 0; n < 4; ++n)
      bfr[n] = dsr128(slr + 16384 + frag_off(wc + n * 16 + (lane & 15), lane));
    if (kt + 2 < NKT) stage(kt + 2, (kt + 2) % 3);
    asm volatile("s_waitcnt lgkmcnt(0)" ::: "memory");
    __builtin_amdgcn_sched_barrier(0);
    __builtin_amdgcn_s_setprio(1);
    #pragma unroll
    for (int m = 0; m < 4; ++m)
      #pragma unroll
      for (int n = 0; n < 4; ++n){
        acc1[m][n] = __builtin_amdgcn_mfma_f32_16x16x32_bf16(a1f[m], bfr[n], acc1[m][n], 0, 0, 0);
        acc2[m][n] = __builtin_amdgcn_mfma_f32_16x16x32_bf16(a2f[m], bfr[n], acc2[m][n], 0, 0, 0);
      }
    __builtin_amdgcn_s_setprio(0);
    if (kt + 2 < NKT)      asm volatile("s_waitcnt vmcnt(6)" ::: "memory");
    else if (kt + 1 < NKT) asm volatile("s_waitcnt vmcnt(0)" ::: "memory");
    __builtin_amdgcn_s_barrier();
  }
  #pragma unroll
  for (int n = 0; n < 4; ++n){
    int col = col0 + wc + n * 16 + (lane & 15);
    float bv = bias[col];
    #pragma unroll
    for (int m = 0; m < 4; ++m){
      int row = row0 + wr + m * 16 + ((lane >> 4) << 2);
      #pragma unroll
      for (int r = 0; r < 4; ++r){
        float so = bf2f(sobf[(size_t)(row + r) * CDIM + col]);
        out[(size_t)(row + r) * CDIM + col] = acc1[m][n][r] * so + acc2[m][n][r] + bv;
      }
    }
  }
}

extern "C" void kernel_launch(void* const* d_in, const int* in_sizes, int n_in,
                              void* d_out, int out_size, void* d_ws, size_t ws_size,
                              hipStream_t stream)
{
  const float* x    = (const float*)d_in[0];
  const float* W    = (const float*)d_in[1];
  const float* bias = (const float*)d_in[2];
  const float* cwo  = (const float*)d_in[3];
  const float* cbo  = (const float*)d_in[4];
  const float* bngo = (const float*)d_in[5];
  const float* bnbo = (const float*)d_in[6];
  const float* bnmo = (const float*)d_in[7];
  const float* bnvo = (const float*)d_in[8];
  const float* ewo  = (const float*)d_in[9];
  const float* ebo  = (const float*)d_in[10];
  const float* cwi  = (const float*)d_in[11];
  const float* cbi  = (const float*)d_in[12];
  const float* bngi = (const float*)d_in[13];
  const float* bnbi = (const float*)d_in[14];
  const float* bnmi = (const float*)d_in[15];
  const float* bnvi = (const float*)d_in[16];
  const float* ewi  = (const float*)d_in[17];
  const float* ebi  = (const float*)d_in[18];
  float* out = (float*)d_out;
  (void)in_sizes; (void)n_in; (void)out_size; (void)ws_size;

  char* ws = (char*)d_ws;
  size_t off = 0;
  auto alloc = [&](size_t bytes){ void* p = ws + off; off += (bytes + 255) & ~(size_t)255; return p; };
  unsigned short* xbf  = (unsigned short*)alloc((size_t)NROWS * CDIM * 2);
  unsigned short* xsbf = (unsigned short*)alloc((size_t)NROWS * CDIM * 2);
  unsigned short* sobf = (unsigned short*)alloc((size_t)NROWS * CDIM * 2);
  float*          Lbuf = (float*)         alloc((size_t)NROWS * CDIM * 4);
  unsigned short* uo   = (unsigned short*)alloc((size_t)NROWS * BNC * 2);
  unsigned short* ui   = (unsigned short*)alloc((size_t)NROWS * BNC * 2);
  unsigned short* wtb  = (unsigned short*)alloc((size_t)CDIM * CDIM * 2);
  unsigned short* e16o = (unsigned short*)alloc((size_t)CDIM * BNC * 2);
  unsigned short* e16i = (unsigned short*)alloc((size_t)CDIM * BNC * 2);

  k_wt<<<dim3(32, 32), dim3(32, 8), 0, stream>>>(W, wtb);
  k_ecast<<<dim3(1024), dim3(256), 0, stream>>>(ewo, ewi, e16o, e16i);
  k_bottleneck<<<dim3(NROWS / 8), dim3(256), 0, stream>>>(
      x, cwo, cbo, bngo, bnbo, bnmo, bnvo,
      cwi, cbi, bngi, bnbi, bnmi, bnvi, xbf, uo, ui);
  k_expand<<<dim3(2048), dim3(256), 0, stream>>>(uo, e16o, ebo, Lbuf);
  k_select<false><<<dim3(NROWS / 4), dim3(256), 0, stream>>>(Lbuf, nullptr, sobf);
  k_expand<<<dim3(2048), dim3(256), 0, stream>>>(ui, e16i, ebi, Lbuf);
  k_select<true><<<dim3(NROWS / 4), dim3(256), 0, stream>>>(Lbuf, xbf, xsbf);
  k_main<<<dim3(2048), dim3(256), 0, stream>>>(xbf, xsbf, wtb, sobf, bias, out);
}

// Round 9
// 369.247 us; speedup vs baseline: 1.3111x; 1.2948x over previous
//
#include <hip/hip_runtime.h>
#include <hip/hip_bf16.h>

typedef __attribute__((ext_vector_type(8))) short short8;
typedef __attribute__((ext_vector_type(8))) _Float16 half8;
typedef __attribute__((ext_vector_type(4))) float f32x4;

#define NROWS 32768
#define CDIM 1024
#define BNC 256
#define TOPK 128
#define NKT 32   // k_main K-tiles of 32

struct alignas(8) U4 { unsigned short x, y, z, w; };

__device__ __forceinline__ unsigned short f2bf(float f){
  union { float f; unsigned u; } v; v.f = f;
  unsigned r = v.u + 0x7FFFu + ((v.u >> 16) & 1u);
  return (unsigned short)(r >> 16);
}
__device__ __forceinline__ float bf2f(unsigned short h){
  union { unsigned u; float f; } v; v.u = ((unsigned)h) << 16;
  return v.f;
}
__device__ __forceinline__ unsigned short f2h(float f){
  _Float16 h = (_Float16)f;
  union { _Float16 h; unsigned short u; } v; v.h = h; return v.u;
}
__device__ __forceinline__ float h2f(unsigned short u){
  union { unsigned short u; _Float16 h; } v; v.u = u; return (float)v.h;
}
__device__ __forceinline__ void gl16(const void* g, void* l){
  __builtin_amdgcn_global_load_lds((const __attribute__((address_space(1))) void*)g,
                                   (__attribute__((address_space(3))) void*)l, 16, 0, 0);
}
__device__ __forceinline__ unsigned ldsaddr(const void* p){
  return (unsigned)(uintptr_t)(const __attribute__((address_space(3))) void*)p;
}
// asm ds_read_b128: invisible to the waitcnt pass -> no auto vmcnt drains against
// outstanding global_load_lds. Correctness: explicit lgkmcnt(0) + sched_barrier(0)
// before the consuming MFMAs (rule #18).
__device__ __forceinline__ short8 dsr128(unsigned addr){
  short8 r;
  asm volatile("ds_read_b128 %0, %1" : "=v"(r) : "v"(addr));
  return r;
}
__device__ __forceinline__ half8 s2h(short8 s){ union { short8 s; half8 h; } u; u.s = s; return u.h; }

// XOR swizzle within rows of 64B (4 granules of 16B): granule g -> g ^ swzf(r).
// Involution: pre-swizzle global source at stage, swizzle offset at read. 2-way = free.
__device__ __forceinline__ int swzf(int r){ return (r & 3) ^ ((r >> 2) & 1); }
__device__ __forceinline__ int swz(int o){ return o ^ (swzf(o >> 6) << 4); }

// stage one [128 rows][32 k] tile (8 KB) into LDS (256-thread blocks)
__device__ __forceinline__ void stage_tile(const unsigned short* g0, int gstride,
                                           char* lds, int tid){
  #pragma unroll
  for (int i = 0; i < 2; ++i){
    int o = tid * 16 + i * 4096;
    int lb = swz(o);
    gl16((const char*)g0 + (lb >> 6) * gstride + (lb & 63), lds + o);
  }
}
__device__ __forceinline__ int frag_off(int ridx, int lane){
  return ridx * 64 + (((lane >> 4) ^ swzf(ridx)) << 4);
}

// ---------------- param prep ----------------
__global__ void k_wt(const float* __restrict__ W, unsigned short* __restrict__ Wt){
  __shared__ float t[32][33];
  int tx = threadIdx.x, ty = threadIdx.y;
  int bx = blockIdx.x * 32, by = blockIdx.y * 32;
  for (int i = ty; i < 32; i += 8)
    t[i][tx] = W[(by + i) * CDIM + bx + tx];
  __syncthreads();
  for (int i = ty; i < 32; i += 8)
    Wt[(bx + i) * CDIM + by + tx] = f2bf(t[tx][i]);
}

__global__ void k_ecast(const float* __restrict__ eo, const float* __restrict__ ei,
                        unsigned short* __restrict__ ho, unsigned short* __restrict__ hi){
  int i = blockIdx.x * 256 + threadIdx.x;
  ho[i] = f2h(eo[i]);
  hi[i] = f2h(ei[i]);
}

// ---------------- bottleneck: grouped conv + BN + GELU (fp16 out), plus x->bf16 ----------------
__global__ __launch_bounds__(256) void k_bottleneck(
    const float* __restrict__ x,
    const float* __restrict__ cwo, const float* __restrict__ cbo,
    const float* __restrict__ go,  const float* __restrict__ bto,
    const float* __restrict__ mo,  const float* __restrict__ vo,
    const float* __restrict__ cwi, const float* __restrict__ cbi,
    const float* __restrict__ gi,  const float* __restrict__ bti,
    const float* __restrict__ mi,  const float* __restrict__ vi,
    unsigned short* __restrict__ xbf,
    unsigned short* __restrict__ uo, unsigned short* __restrict__ ui)
{
  const int t = threadIdx.x;
  const int r0 = blockIdx.x * 8;
  float4 cwov = ((const float4*)cwo)[t];
  float4 cwiv = ((const float4*)cwi)[t];
  float sco = go[t] * rsqrtf(vo[t] + 1e-5f);
  float sho = bto[t] - mo[t] * sco;
  float cbov = cbo[t];
  float sci = gi[t] * rsqrtf(vi[t] + 1e-5f);
  float shi = bti[t] - mi[t] * sci;
  float cbiv = cbi[t];
  for (int r = 0; r < 8; ++r){
    int row = r0 + r;
    float4 xv = ((const float4*)x)[row * 256 + t];
    U4 xb; xb.x = f2bf(xv.x); xb.y = f2bf(xv.y); xb.z = f2bf(xv.z); xb.w = f2bf(xv.w);
    ((U4*)xbf)[row * 256 + t] = xb;
    float h = xv.x*cwov.x + xv.y*cwov.y + xv.z*cwov.z + xv.w*cwov.w + cbov;
    h = h * sco + sho;
    float u = 0.5f * h * (1.0f + erff(h * 0.70710678118654752f));
    uo[row*BNC + t] = f2h(u);
    h = xv.x*cwiv.x + xv.y*cwiv.y + xv.z*cwiv.z + xv.w*cwiv.w + cbiv;
    h = h * sci + shi;
    u = 0.5f * h * (1.0f + erff(h * 0.70710678118654752f));
    ui[row*BNC + t] = f2h(u);
  }
}

// ---------------- expand GEMM (fp16): L = U@E^T + eb -> fp16 Lbuf ----------------
__global__ __launch_bounds__(256, 3) void k_expand(
    const unsigned short* __restrict__ u16, const unsigned short* __restrict__ e16,
    const float* __restrict__ eb, unsigned short* __restrict__ Lout)
{
  __shared__ alignas(16) char lds[3 * 16384];
  const int tid = threadIdx.x;
  const int lane = tid & 63, w = tid >> 6;
  const int wr = (w >> 1) * 64, wc = (w & 1) * 64;
  int id = blockIdx.x;
  int xcd = id & 7, slot = id >> 3;
  const int row0 = (xcd * 32 + (slot >> 3)) * 128;
  const int col0 = (slot & 7) * 128;
  f32x4 acc[4][4] = {};
  auto stage = [&](int h, int buf){
    char* b = lds + buf * 16384;
    stage_tile(u16 + row0 * BNC + h * 32, 512, b, tid);
    stage_tile(e16 + col0 * BNC + h * 32, 512, b + 8192, tid);
  };
  stage(0, 0);
  stage(1, 1);
  asm volatile("s_waitcnt vmcnt(4)" ::: "memory");
  __builtin_amdgcn_s_barrier();
  const unsigned lbase = ldsaddr(lds);
  const int NK = BNC / 32;
  for (int h = 0; h < NK; ++h){
    unsigned sl = lbase + (h % 3) * 16384;
    short8 af[4], bfr[4];
    #pragma unroll
    for (int m = 0; m < 4; ++m) af[m]  = dsr128(sl + frag_off(wr + m * 16 + (lane & 15), lane));
    #pragma unroll
    for (int n = 0; n < 4; ++n) bfr[n] = dsr128(sl + 8192 + frag_off(wc + n * 16 + (lane & 15), lane));
    if (h + 2 < NK) stage(h + 2, (h + 2) % 3);
    __builtin_amdgcn_s_barrier();
    asm volatile("s_waitcnt lgkmcnt(0)" ::: "memory");
    __builtin_amdgcn_sched_barrier(0);
    __builtin_amdgcn_s_setprio(1);
    #pragma unroll
    for (int m = 0; m < 4; ++m)
      #pragma unroll
      for (int n = 0; n < 4; ++n)
        acc[m][n] = __builtin_amdgcn_mfma_f32_16x16x32_f16(s2h(af[m]), s2h(bfr[n]), acc[m][n], 0, 0, 0);
    __builtin_amdgcn_s_setprio(0);
    if (h + 2 < NK)      asm volatile("s_waitcnt vmcnt(4)" ::: "memory");
    else if (h + 1 < NK) asm volatile("s_waitcnt vmcnt(0)" ::: "memory");
    __builtin_amdgcn_s_barrier();
  }
  #pragma unroll
  for (int n = 0; n < 4; ++n){
    int col = col0 + wc + n * 16 + (lane & 15);
    float ebv = eb[col];
    #pragma unroll
    for (int m = 0; m < 4; ++m){
      int row = row0 + wr + m * 16 + ((lane >> 4) << 2);
      #pragma unroll
      for (int r = 0; r < 4; ++r)
        Lout[(size_t)(row + r) * CDIM + col] = f2h(acc[m][n][r] + ebv);
    }
  }
}

// ---------------- softmax + top-128 threshold + sparse score (fp16 L) ----------------
// 16-bit monotone-key radix search (16 iters) with ballot+popcount counting.
// XCD-aligned rows: block id = xcd + 8*(q*32 + b); panel = xcd*32+q matches k_expand's
// writer XCD so Lbuf reads hit that XCD's L2.
template<bool WRITE_XS>
__global__ __launch_bounds__(256) void k_select(
    const unsigned short* __restrict__ Lg, const unsigned short* __restrict__ xg,
    unsigned short* __restrict__ obf)
{
  const int lane = threadIdx.x & 63;
  const int wv = threadIdx.x >> 6;
  int id = blockIdx.x;
  int xcd = id & 7, rest = id >> 3;
  int q = rest >> 5, b = rest & 31;
  const int row = (xcd * 32 + q) * 128 + b * 4 + wv;
  const unsigned short* Lr = Lg + (size_t)row * CDIM;
  unsigned short hv[16];
  #pragma unroll
  for (int c = 0; c < 2; ++c){
    short8 t8 = ((const short8*)Lr)[c * 64 + lane];
    #pragma unroll
    for (int j = 0; j < 8; ++j) hv[c*8+j] = (unsigned short)t8[j];
  }
  // monotone 16-bit keys
  unsigned kx[16];
  #pragma unroll
  for (int j = 0; j < 16; ++j){
    unsigned u = hv[j];
    kx[j] = u ^ ((u & 0x8000u) ? 0xFFFFu : 0x8000u);
  }
  // wave max / exp-sum (fp32)
  float v[16];
  #pragma unroll
  for (int j = 0; j < 16; ++j) v[j] = h2f(hv[j]);
  float M = v[0];
  #pragma unroll
  for (int j = 1; j < 16; ++j) M = fmaxf(M, v[j]);
  #pragma unroll
  for (int off = 32; off > 0; off >>= 1) M = fmaxf(M, __shfl_xor(M, off));
  float e[16];
  float S = 0.f;
  #pragma unroll
  for (int j = 0; j < 16; ++j){ e[j] = expf(v[j] - M); S += e[j]; }
  #pragma unroll
  for (int off = 32; off > 0; off >>= 1) S += __shfl_xor(S, off);
  // 16-iteration threshold search; count via ballot+popcount (scalar pipe)
  unsigned pref = 0;
  for (int bit = 15; bit >= 0; --bit){
    unsigned cand = pref | (1u << bit);
    int c = 0;
    #pragma unroll
    for (int j = 0; j < 16; ++j)
      c += (int)__popcll(__ballot(kx[j] >= cand));
    if (c >= TOPK) pref = cand;
  }
  float invS = 1.0f / S;
  #pragma unroll
  for (int c = 0; c < 2; ++c){
    unsigned short o8[8];
    #pragma unroll
    for (int j = 0; j < 8; ++j){
      int jj = c*8 + j;
      float sc = (kx[jj] >= pref) ? e[jj] * invS : 0.f;
      o8[j] = f2bf(sc);
    }
    if (WRITE_XS){
      short8 xv = ((const short8*)(xg + (size_t)row * CDIM))[c * 64 + lane];
      #pragma unroll
      for (int j = 0; j < 8; ++j){
        float sc = bf2f(o8[j]);
        // recompute exact product in fp32 from cached e[] to avoid double-rounding of sc
        int jj = c*8 + j;
        float scf = (kx[jj] >= pref) ? e[jj] * invS : 0.f;
        (void)sc;
        o8[j] = f2bf(bf2f((unsigned short)xv[j]) * scf);
      }
    }
    short8 st;
    #pragma unroll
    for (int j = 0; j < 8; ++j) st[j] = (short)o8[j];
    ((short8*)(obf + (size_t)row * CDIM))[c * 64 + lane] = st;
  }
}

// ---------------- main dual-A GEMM: 128x128, 3-slot lead-2, 2 blocks/CU ----------------
// (round-8 known-good; frozen as control)
__global__ __launch_bounds__(256, 2) void k_main(
    const unsigned short* __restrict__ xbf, const unsigned short* __restrict__ xsbf,
    const unsigned short* __restrict__ wt,  const unsigned short* __restrict__ sobf,
    const float* __restrict__ bias, float* __restrict__ out)
{
  __shared__ alignas(16) char lds[3 * 24576];
  const int tid = threadIdx.x;
  const int lane = tid & 63, w = tid >> 6;
  const int wr = (w >> 1) * 64, wc = (w & 1) * 64;
  int id = blockIdx.x;
  int xcd = id & 7, sl = id >> 3;
  const int row0 = (xcd * 32 + (sl >> 3)) * 128;
  const int col0 = (sl & 7) * 128;
  f32x4 acc1[4][4] = {}, acc2[4][4] = {};
  auto stage = [&](int kt, int buf){
    char* b = lds + buf * 24576;
    stage_tile(xbf  + row0 * CDIM + kt * 32, 2048, b, tid);
    stage_tile(xsbf + row0 * CDIM + kt * 32, 2048, b + 8192, tid);
    stage_tile(wt   + col0 * CDIM + kt * 32, 2048, b + 16384, tid);
  };
  stage(0, 0);
  stage(1, 1);
  asm volatile("s_waitcnt vmcnt(6)" ::: "memory");
  __builtin_amdgcn_s_barrier();
  const unsigned lbase = ldsaddr(lds);
  for (int kt = 0; kt < NKT; ++kt){
    const unsigned slr = lbase + (kt % 3) * 24576;
    short8 a1f[4], a2f[4], bfr[4];
    #pragma unroll
    for (int m = 0; m < 4; ++m){
      int fo = frag_off(wr + m * 16 + (lane & 15), lane);
      a1f[m] = dsr128(slr + fo);
      a2f[m] = dsr128(slr + 8192 + fo);
    }
    #pragma unroll
    for (int n = 0; n < 4; ++n)
      bfr[n] = dsr128(slr + 16384 + frag_off(wc + n * 16 + (lane & 15), lane));
    if (kt + 2 < NKT) stage(kt + 2, (kt + 2) % 3);
    asm volatile("s_waitcnt lgkmcnt(0)" ::: "memory");
    __builtin_amdgcn_sched_barrier(0);
    __builtin_amdgcn_s_setprio(1);
    #pragma unroll
    for (int m = 0; m < 4; ++m)
      #pragma unroll
      for (int n = 0; n < 4; ++n){
        acc1[m][n] = __builtin_amdgcn_mfma_f32_16x16x32_bf16(a1f[m], bfr[n], acc1[m][n], 0, 0, 0);
        acc2[m][n] = __builtin_amdgcn_mfma_f32_16x16x32_bf16(a2f[m], bfr[n], acc2[m][n], 0, 0, 0);
      }
    __builtin_amdgcn_s_setprio(0);
    if (kt + 2 < NKT)      asm volatile("s_waitcnt vmcnt(6)" ::: "memory");
    else if (kt + 1 < NKT) asm volatile("s_waitcnt vmcnt(0)" ::: "memory");
    __builtin_amdgcn_s_barrier();
  }
  #pragma unroll
  for (int n = 0; n < 4; ++n){
    int col = col0 + wc + n * 16 + (lane & 15);
    float bv = bias[col];
    #pragma unroll
    for (int m = 0; m < 4; ++m){
      int row = row0 + wr + m * 16 + ((lane >> 4) << 2);
      #pragma unroll
      for (int r = 0; r < 4; ++r){
        float so = bf2f(sobf[(size_t)(row + r) * CDIM + col]);
        out[(size_t)(row + r) * CDIM + col] = acc1[m][n][r] * so + acc2[m][n][r] + bv;
      }
    }
  }
}

extern "C" void kernel_launch(void* const* d_in, const int* in_sizes, int n_in,
                              void* d_out, int out_size, void* d_ws, size_t ws_size,
                              hipStream_t stream)
{
  const float* x    = (const float*)d_in[0];
  const float* W    = (const float*)d_in[1];
  const float* bias = (const float*)d_in[2];
  const float* cwo  = (const float*)d_in[3];
  const float* cbo  = (const float*)d_in[4];
  const float* bngo = (const float*)d_in[5];
  const float* bnbo = (const float*)d_in[6];
  const float* bnmo = (const float*)d_in[7];
  const float* bnvo = (const float*)d_in[8];
  const float* ewo  = (const float*)d_in[9];
  const float* ebo  = (const float*)d_in[10];
  const float* cwi  = (const float*)d_in[11];
  const float* cbi  = (const float*)d_in[12];
  const float* bngi = (const float*)d_in[13];
  const float* bnbi = (const float*)d_in[14];
  const float* bnmi = (const float*)d_in[15];
  const float* bnvi = (const float*)d_in[16];
  const float* ewi  = (const float*)d_in[17];
  const float* ebi  = (const float*)d_in[18];
  float* out = (float*)d_out;
  (void)in_sizes; (void)n_in; (void)out_size; (void)ws_size;

  char* ws = (char*)d_ws;
  size_t off = 0;
  auto alloc = [&](size_t bytes){ void* p = ws + off; off += (bytes + 255) & ~(size_t)255; return p; };
  unsigned short* xbf  = (unsigned short*)alloc((size_t)NROWS * CDIM * 2);
  unsigned short* xsbf = (unsigned short*)alloc((size_t)NROWS * CDIM * 2);
  unsigned short* sobf = (unsigned short*)alloc((size_t)NROWS * CDIM * 2);
  unsigned short* Lbuf = (unsigned short*)alloc((size_t)NROWS * CDIM * 2);
  unsigned short* uo   = (unsigned short*)alloc((size_t)NROWS * BNC * 2);
  unsigned short* ui   = (unsigned short*)alloc((size_t)NROWS * BNC * 2);
  unsigned short* wtb  = (unsigned short*)alloc((size_t)CDIM * CDIM * 2);
  unsigned short* e16o = (unsigned short*)alloc((size_t)CDIM * BNC * 2);
  unsigned short* e16i = (unsigned short*)alloc((size_t)CDIM * BNC * 2);

  k_wt<<<dim3(32, 32), dim3(32, 8), 0, stream>>>(W, wtb);
  k_ecast<<<dim3(1024), dim3(256), 0, stream>>>(ewo, ewi, e16o, e16i);
  k_bottleneck<<<dim3(NROWS / 8), dim3(256), 0, stream>>>(
      x, cwo, cbo, bngo, bnbo, bnmo, bnvo,
      cwi, cbi, bngi, bnbi, bnmi, bnvi, xbf, uo, ui);
  k_expand<<<dim3(2048), dim3(256), 0, stream>>>(uo, e16o, ebo, Lbuf);
  k_select<false><<<dim3(NROWS / 4), dim3(256), 0, stream>>>(Lbuf, nullptr, sobf);
  k_expand<<<dim3(2048), dim3(256), 0, stream>>>(ui, e16i, ebi, Lbuf);
  k_select<true><<<dim3(NROWS / 4), dim3(256), 0, stream>>>(Lbuf, xbf, xsbf);
  k_main<<<dim3(2048), dim3(256), 0, stream>>>(xbf, xsbf, wtb, sobf, bias, out);
}